// Round 2
// 84.353 us; speedup vs baseline: 1.0128x; 1.0128x over previous
//
#include <hip/hip_runtime.h>

// QuanvolutionClassifier — fully fused single kernel.
// R3: U = U01 (x) U23 factorization (CX(0,1), CX(2,3) never couple pairs).
// R4: fuse build_U into the main kernel; 32 coeffs pinned to SGPRs via rfl.
// R5: phase-1 pair-fusion — two adjacent patches per task via two float4
//     loads (halves VMEM instruction count and per-task address math);
//     fast trig in the U-build serial section.
// R6: identical to R5 — previous round died on container infra, resubmit.

#define RPB 4           // rows (batch images) per block
#define NPIX 784
#define NPATCH 196
#define NPAIR 98        // 14 patch-rows x 7 horizontal patch-pairs

__device__ __forceinline__ float rfl(float v) {
    return __uint_as_float(__builtin_amdgcn_readfirstlane(__float_as_uint(v)));
}

__launch_bounds__(256, 8)   // 8 waves/EU -> VGPR<=64, 8 blocks/CU, 32 waves/CU
__global__ void quanv_kernel(const float* __restrict__ x,
                             const float* __restrict__ params,
                             const float* __restrict__ W,
                             const float* __restrict__ bias,
                             float* __restrict__ out,
                             int n_rows) {
    __shared__ __align__(16) float feat[RPB * NPIX];   // 12544 B
    __shared__ float Ush[32];                          // U01 | U23
    const int tid = threadIdx.x;
    const int row0 = blockIdx.x * RPB;

    // ---- build U01/U23 (8 lanes, ~100 FLOPs, redundant per block) ----
    if (tid < 8) {
        int pair = tid >> 2;      // 0 -> wires {0,1}, 1 -> wires {2,3}
        int col  = tid & 3;       // basis column
        float st[4];
#pragma unroll
        for (int i = 0; i < 4; ++i) st[i] = (i == col) ? 1.0f : 0.0f;
#pragma unroll
        for (int l = 0; l < 4; ++l) {
            float ah = 0.5f * params[l * 4 + pair * 2 + 0];   // high wire of pair
            float al = 0.5f * params[l * 4 + pair * 2 + 1];   // low wire of pair
            float ch = __cosf(ah), sh = __sinf(ah);
#pragma unroll
            for (int j = 0; j < 2; ++j) {                     // RY on high bit
                float u = st[j], w = st[j + 2];
                st[j]     = ch * u - sh * w;
                st[j + 2] = sh * u + ch * w;
            }
            float cl = __cosf(al), sl = __sinf(al);
#pragma unroll
            for (int j = 0; j < 4; j += 2) {                  // RY on low bit
                float u = st[j], w = st[j + 1];
                st[j]     = cl * u - sl * w;
                st[j + 1] = sl * u + cl * w;
            }
            float tmp = st[2]; st[2] = st[3]; st[3] = tmp;    // CX: swap |10>,|11>
        }
#pragma unroll
        for (int s = 0; s < 4; ++s) Ush[pair * 16 + s * 4 + col] = st[s];
    }
    __syncthreads();

    // pin the 32 wave-uniform coeffs into SGPRs
    float Ua[16], Ub[16];
#pragma unroll
    for (int i = 0; i < 16; ++i) { Ua[i] = rfl(Ush[i]); Ub[i] = rfl(Ush[16 + i]); }

    // one patch: angles (a0,a1) = top pixels, (a2,a3) = bottom pixels
    auto quanv1 = [&](float a0, float a1, float a2, float a3) -> float4 {
        float c0 = __cosf(0.5f * a0), s0 = __sinf(0.5f * a0);
        float c1 = __cosf(0.5f * a1), s1 = __sinf(0.5f * a1);
        float c2 = __cosf(0.5f * a2), s2 = __sinf(0.5f * a2);
        float c3 = __cosf(0.5f * a3), s3 = __sinf(0.5f * a3);
        float pa[4] = { c0 * c1, c0 * s1, s0 * c1, s0 * s1 };
        float pb[4] = { c2 * c3, c2 * s3, s2 * c3, s2 * s3 };
        float qa[4], qb[4];
#pragma unroll
        for (int s = 0; s < 4; ++s) {
            float ya = fmaf(Ua[s * 4 + 3], pa[3],
                       fmaf(Ua[s * 4 + 2], pa[2],
                       fmaf(Ua[s * 4 + 1], pa[1], Ua[s * 4 + 0] * pa[0])));
            float yb = fmaf(Ub[s * 4 + 3], pb[3],
                       fmaf(Ub[s * 4 + 2], pb[2],
                       fmaf(Ub[s * 4 + 1], pb[1], Ub[s * 4 + 0] * pb[0])));
            qa[s] = ya * ya;
            qb[s] = yb * yb;
        }
        float4 e;
        e.x = (qa[0] + qa[1]) - (qa[2] + qa[3]);   // Z wire0
        e.y = (qa[0] - qa[1]) + (qa[2] - qa[3]);   // Z wire1
        e.z = (qb[0] + qb[1]) - (qb[2] + qb[3]);   // Z wire2
        e.w = (qb[0] - qb[1]) + (qb[2] - qb[3]);   // Z wire3
        return e;
    };

    // ------------- phase 1: per-patch-PAIR quantum features -------------
    for (int g = tid; g < RPB * NPAIR; g += 256) {
        int r = g / NPAIR;                  // local row in block
        int t = g - r * NPAIR;              // pair id 0..97
        int grow = row0 + r;
        float4 eA = make_float4(0.f, 0.f, 0.f, 0.f);
        float4 eB = eA;
        if (grow < n_rows) {
            int Pr = t / 7;                 // patch row 0..13
            int Pp = t - Pr * 7;            // pair col 0..6 (patches 2Pp, 2Pp+1)
            const float* px = x + (size_t)grow * NPIX + Pr * 56 + Pp * 4;
            float4 T  = *(const float4*)px;          // image row 2Pr, cols 4Pp..4Pp+3
            float4 Bt = *(const float4*)(px + 28);   // image row 2Pr+1
            eA = quanv1(T.x, T.y, Bt.x, Bt.y);       // patch (Pr, 2Pp)
            eB = quanv1(T.z, T.w, Bt.z, Bt.w);       // patch (Pr, 2Pp+1)
        }
        // feat index 4*P with P = Pr*14 + 2Pp  ->  56*Pr + 8*Pp = 8*t
        *(float4*)&feat[r * NPIX + 8 * t]     = eA;
        *(float4*)&feat[r * NPIX + 8 * t + 4] = eB;
    }
    __syncthreads();

    // ---------------- phase 2: feat @ W^T + b, log_softmax ----------------
    const int wid = tid >> 6, lane = tid & 63;
    const float4* W4 = (const float4*)W;               // W4[o*196 + k]
    for (int r = wid; r < RPB; r += 4) {
        int grow = row0 + r;
        if (grow >= n_rows) break;
        float acc[10];
#pragma unroll
        for (int o = 0; o < 10; ++o) acc[o] = 0.f;
        const float4* frow4 = (const float4*)&feat[r * NPIX];   // 196 float4
        for (int k = lane; k < NPATCH; k += 64) {
            float4 f = frow4[k];
#pragma unroll
            for (int o = 0; o < 10; ++o) {
                float4 w = W4[o * NPATCH + k];
                acc[o] = fmaf(f.x, w.x, fmaf(f.y, w.y, fmaf(f.z, w.z, fmaf(f.w, w.w, acc[o]))));
            }
        }
#pragma unroll
        for (int o = 0; o < 10; ++o) {
            acc[o] += __shfl_xor(acc[o], 32, 64);
            acc[o] += __shfl_xor(acc[o], 16, 64);
            acc[o] += __shfl_xor(acc[o], 8, 64);
            acc[o] += __shfl_xor(acc[o], 4, 64);
            acc[o] += __shfl_xor(acc[o], 2, 64);
            acc[o] += __shfl_xor(acc[o], 1, 64);
        }
        if (lane == 0) {
            float lg[10], mx = -1e30f;
#pragma unroll
            for (int o = 0; o < 10; ++o) { lg[o] = acc[o] + bias[o]; mx = fmaxf(mx, lg[o]); }
            float sum = 0.f;
#pragma unroll
            for (int o = 0; o < 10; ++o) sum += __expf(lg[o] - mx);
            float lse = mx + __logf(sum);
#pragma unroll
            for (int o = 0; o < 10; ++o) out[(size_t)grow * 10 + o] = lg[o] - lse;
        }
    }
}

extern "C" void kernel_launch(void* const* d_in, const int* in_sizes, int n_in,
                              void* d_out, int out_size, void* d_ws, size_t ws_size,
                              hipStream_t stream) {
    const float* x      = (const float*)d_in[0];
    const float* params = (const float*)d_in[1];
    const float* W      = (const float*)d_in[2];
    const float* b      = (const float*)d_in[3];
    float* out = (float*)d_out;

    int n_rows = in_sizes[0] / NPIX;   // 8192
    int nblocks = (n_rows + RPB - 1) / RPB;
    hipLaunchKernelGGL(quanv_kernel, dim3(nblocks), dim3(256), 0, stream,
                       x, params, W, b, out, n_rows);
}